// Round 1
// 6539.105 us; speedup vs baseline: 1.0441x; 1.0441x over previous
//
#include <hip/hip_runtime.h>

#define HD 300
#define KC 75
#define BD 64
#define VD 100000
#define LD 64
#define NM32 3126            // number of 32-row vocab groups (3126*32 = 100032)
#define NT16 6252            // number of 16-row vocab tiles
#define MARGIN 0.05f

typedef unsigned long long u64;
typedef short short8 __attribute__((ext_vector_type(8)));
typedef float f32x4 __attribute__((ext_vector_type(4)));

__device__ __forceinline__ float sigm(float x) { return 1.0f / (1.0f + expf(-x)); }

// Transposed k-chunked layout: T[kc][b][e] = X[b][4*kc+e].
__device__ __forceinline__ int tidx(int k, int b) {
  return (k >> 2) * 256 + b * 4 + (k & 3);
}

__device__ __forceinline__ unsigned enc32(float f) {
  unsigned u = __float_as_uint(f);
  return (u & 0x80000000u) ? ~u : (u | 0x80000000u);
}
__device__ __forceinline__ float dec32(unsigned e) {
  unsigned u = (e & 0x80000000u) ? (e & 0x7FFFFFFFu) : ~e;
  return __uint_as_float(u);
}
__device__ __forceinline__ unsigned short f2bf(float f) {   // RNE
  unsigned u = __float_as_uint(f);
  unsigned r = u + 0x7FFFu + ((u >> 16) & 1u);
  return (unsigned short)(r >> 16);
}
__device__ __forceinline__ u64 shfl64(u64 v, int m) {
  int lo = __shfl_xor((int)(unsigned)v, m, 64);
  int hi = __shfl_xor((int)(unsigned)(v >> 32), m, 64);
  return ((u64)(unsigned)hi << 32) | (unsigned)lo;
}
__device__ __forceinline__ u64 umax64(u64 a, u64 b) { return a > b ? a : b; }
__device__ __forceinline__ void top2(u64 k, u64& b, u64& r) {
  if (k > b) { r = b; b = k; } else if (k > r) r = k;
}

// ---------------------------------------------------------------------------
// k_prep: gather token embeddings into transposed k-chunked layout.
// ---------------------------------------------------------------------------
__global__ __launch_bounds__(320) void k_prep(
    const int* __restrict__ input, const float* __restrict__ emb,
    float* __restrict__ xall)
{
  const int t = blockIdx.x, b = blockIdx.y;
  const int k = threadIdx.x;
  if (k >= HD) return;
  const int id = input[t * BD + b];
  xall[t * (KC * 256) + tidx(k, b)] = emb[(size_t)id * HD + k];
}

// ---------------------------------------------------------------------------
// k_init: h0 = 0, first decoder x = relu(emb[0]); also zero hbp once so the
// k>=300 pad entries of the packed-h buffer stay zero for all decoder steps
// (the fused GRU pack only writes k<300).
// ---------------------------------------------------------------------------
__global__ __launch_bounds__(320) void k_init(
    float* __restrict__ hT, const float* __restrict__ emb, float* __restrict__ xdec,
    unsigned* __restrict__ hbp)
{
  const int b = blockIdx.x;
  const int k = threadIdx.x;
  const int gi = b * 320 + k;
  if (gi < 10240) hbp[gi] = 0u;
  if (k >= HD) return;
  hT[tidx(k, b)] = 0.f;
  xdec[tidx(k, b)] = fmaxf(emb[k], 0.f);
}

// ---------------------------------------------------------------------------
// k_gru: split-K (two halves of the 75-iteration K loop run in parallel on
// 12 waves, combined through LDS) to halve the serial latency chain.
// PACK=true additionally packs the 4 fresh h rows into hbp in MFMA B-fragment
// order (replaces the old k_packh launch).
// ---------------------------------------------------------------------------
template <bool PACK>
__global__ __launch_bounds__(768) void k_gru(
    const float* __restrict__ xT, const float* __restrict__ hT_in,
    const float* __restrict__ W_ih, const float* __restrict__ W_hh,
    const float* __restrict__ b_ih, const float* __restrict__ b_hh,
    float* __restrict__ hT_out, unsigned* __restrict__ hbp)
{
  const int w = __builtin_amdgcn_readfirstlane(threadIdx.x >> 6);  // 0..11
  const int b = threadIdx.x & 63;
  const int half = (w >= 6) ? 1 : 0;
  const int ww = w - 6 * half;
  const int m = ww & 1;
  const int g = ww >> 1;
  const int i0 = blockIdx.x * 4;

  const float* src = m ? hT_in : xT;
  const float* M   = m ? W_hh : W_ih;
  const float* row0 = M + (size_t)(g * HD + i0) * HD;

  float4 a0 = {0,0,0,0}, a1 = {0,0,0,0}, a2 = {0,0,0,0}, a3 = {0,0,0,0};

  const int kcB = half ? 38 : 0;
  const int kcE = half ? KC : 38;
  for (int kc = kcB; kc < kcE; kc++) {
    const float4 s = *(const float4*)(src + kc * 256 + b * 4);
    const float4 w0 = *(const float4*)(row0 + kc * 4);
    const float4 w1 = *(const float4*)(row0 + HD + kc * 4);
    const float4 w2 = *(const float4*)(row0 + 2 * HD + kc * 4);
    const float4 w3 = *(const float4*)(row0 + 3 * HD + kc * 4);
    a0.x += w0.x * s.x; a0.y += w0.y * s.y; a0.z += w0.z * s.z; a0.w += w0.w * s.w;
    a1.x += w1.x * s.x; a1.y += w1.y * s.y; a1.z += w1.z * s.z; a1.w += w1.w * s.w;
    a2.x += w2.x * s.x; a2.y += w2.y * s.y; a2.z += w2.z * s.z; a2.w += w2.w * s.w;
    a3.x += w3.x * s.x; a3.y += w3.y * s.y; a3.z += w3.z * s.z; a3.w += w3.w * s.w;
  }

  const float* bias = m ? b_hh : b_ih;
  __shared__ float sg[2][2][3][4][64];   // [half][m][g][r][b]
  const float bb0 = half ? 0.f : bias[g * HD + i0 + 0];
  const float bb1 = half ? 0.f : bias[g * HD + i0 + 1];
  const float bb2 = half ? 0.f : bias[g * HD + i0 + 2];
  const float bb3 = half ? 0.f : bias[g * HD + i0 + 3];
  sg[half][m][g][0][b] = (a0.x + a0.y) + (a0.z + a0.w) + bb0;
  sg[half][m][g][1][b] = (a1.x + a1.y) + (a1.z + a1.w) + bb1;
  sg[half][m][g][2][b] = (a2.x + a2.y) + (a2.z + a2.w) + bb2;
  sg[half][m][g][3][b] = (a3.x + a3.y) + (a3.z + a3.w) + bb3;

  __shared__ float hsh[4][64];
  __syncthreads();

  if (w < 4) {
    const int r = w;
    const int i = i0 + r;
    const float xr = sg[0][0][0][r][b] + sg[1][0][0][r][b];
    const float hr = sg[0][1][0][r][b] + sg[1][1][0][r][b];
    const float xz = sg[0][0][1][r][b] + sg[1][0][1][r][b];
    const float hz = sg[0][1][1][r][b] + sg[1][1][1][r][b];
    const float xn = sg[0][0][2][r][b] + sg[1][0][2][r][b];
    const float hn = sg[0][1][2][r][b] + sg[1][1][2][r][b];
    const float rr = sigm(xr + hr);
    const float zz = sigm(xz + hz);
    const float nn = tanhf(xn + rr * hn);
    const float hp = hT_in[tidx(i, b)];
    const float h  = (1.f - zz) * nn + zz * hp;
    hT_out[tidx(i, b)] = h;
    if (PACK) hsh[r][b] = h;
  }

  if (PACK) {
    __syncthreads();
    if (w < 2) {
      // pack the even k-pair (i0 + 2w, i0 + 2w + 1) for all 64 batch cols
      const int k = i0 + 2 * w;
      const unsigned outp =
          (unsigned)f2bf(hsh[2 * w][b]) | ((unsigned)f2bf(hsh[2 * w + 1][b]) << 16);
      const int kt = k >> 5;
      const int q  = (k >> 3) & 3;
      const int p  = (k >> 1) & 3;
      const int nt = b >> 4;
      const int ln = q * 16 + (b & 15);
      hbp[((kt * 4 + nt) << 8) + ln * 4 + p] = outp;
    }
  }
}

// ---------------------------------------------------------------------------
// k_pack: outW fp32 -> Wp bf16 in MFMA A-fragment order. Chunk (t16, kt) is
// 1 KB: [lane(64)][j(8)] with v = t16*16 + (lane&15), k = kt*32 + (lane>>4)*8 + j.
// ---------------------------------------------------------------------------
__global__ __launch_bounds__(256) void k_pack(
    const float* __restrict__ outW, unsigned* __restrict__ Wp)
{
  const int t16 = blockIdx.x;
  const int d = threadIdx.x;          // 0..255: lane = d>>2, pair p = d&3
  const int lane = d >> 2, p = d & 3;
  const int v = t16 * 16 + (lane & 15);
  for (int kt = 0; kt < 10; kt++) {
    const int k = kt * 32 + (lane >> 4) * 8 + 2 * p;
    float f0 = 0.f, f1 = 0.f;
    if (v < VD) {
      if (k < HD)     f0 = outW[(size_t)v * HD + k];
      if (k + 1 < HD) f1 = outW[(size_t)v * HD + k + 1];
    }
    const unsigned out = (unsigned)f2bf(f0) | ((unsigned)f2bf(f1) << 16);
    Wp[((size_t)t16 * 10 + kt) * 256 + d] = out;
  }
}

// ---------------------------------------------------------------------------
// k_projbf: MFMA projection + per-32-row-group top-2 argmax keys.
// 782 blocks x 256 thr (4 waves). Register double-buffer on A-fragments:
// kt=0 loads issued before the staging barrier; the statically unrolled kt
// loop prefetches kt+1 while the MFMAs of kt run.
// ---------------------------------------------------------------------------
template <bool PACKED>
__global__ __launch_bounds__(256) void k_projbf(
    const unsigned* __restrict__ Wp, const float* __restrict__ outW,
    const unsigned* __restrict__ hbp, const float* __restrict__ outb,
    u64* __restrict__ bbuf)
{
  __shared__ __align__(16) unsigned hlds[10240];

  const int w = __builtin_amdgcn_readfirstlane(threadIdx.x >> 6);
  const int lane = threadIdx.x & 63;
  const int m32 = blockIdx.x * 4 + w;
  const int m32c = (m32 < NM32) ? m32 : (NM32 - 1);  // clamp for the dead wave
  const int t0 = m32c * 2;
  const int quad = lane >> 4;

  f32x4 acc[2][4];
#pragma unroll
  for (int mt = 0; mt < 2; mt++)
#pragma unroll
    for (int nt = 0; nt < 4; nt++) acc[mt][nt] = f32x4{0.f, 0.f, 0.f, 0.f};

  auto LOADA = [&](short8* dst, int kt) {
    if (PACKED) {
#pragma unroll
      for (int mt = 0; mt < 2; mt++)
        dst[mt] = *(const short8*)(Wp + ((size_t)(t0 + mt) * 10 + kt) * 256 + lane * 4);
    } else {
#pragma unroll
      for (int mt = 0; mt < 2; mt++) {
        const int v = (t0 + mt) * 16 + (lane & 15);
        const int kb = kt * 32 + quad * 8;
        const int vc = (v < VD) ? v : (VD - 1);
        short8 tmp;
#pragma unroll
        for (int e = 0; e < 8; e++) {
          const int kk = kb + e;
          const float f = (kk < HD && v < VD) ? outW[(size_t)vc * HD + kk] : 0.f;
          tmp[e] = (short)f2bf(f);
        }
        dst[mt] = tmp;
      }
    }
  };

  auto COMPUTE = [&](short8* a, int kt) {
#pragma unroll
    for (int nt = 0; nt < 4; nt++) {
      const short8 bf = *(const short8*)(&hlds[((kt * 4 + nt) << 8) + lane * 4]);
      acc[0][nt] = __builtin_amdgcn_mfma_f32_16x16x32_bf16(a[0], bf, acc[0][nt], 0, 0, 0);
      acc[1][nt] = __builtin_amdgcn_mfma_f32_16x16x32_bf16(a[1], bf, acc[1][nt], 0, 0, 0);
    }
  };

  short8 aA[2], aB[2];
  LOADA(aA, 0);                               // in flight during staging

  {
    const uint4* hb4 = (const uint4*)hbp;
    uint4* hl4 = (uint4*)hlds;
    for (int i = threadIdx.x; i < 2560; i += 256) hl4[i] = hb4[i];
  }
  __syncthreads();
  if (m32 >= NM32) return;

#pragma unroll
  for (int kp = 0; kp < 5; kp++) {
    LOADA(aB, 2 * kp + 1);
    COMPUTE(aA, 2 * kp);
    if (kp < 4) LOADA(aA, 2 * kp + 2);
    COMPUTE(aB, 2 * kp + 1);
  }

  // ---- epilogue: top2 per batch column ----
  const int m0 = m32 * 32;
  u64 best[4], run[4];
#pragma unroll
  for (int nt = 0; nt < 4; nt++) { best[nt] = 0ull; run[nt] = 0ull; }

#pragma unroll
  for (int mt = 0; mt < 2; mt++) {
    const int vb = m0 + mt * 16 + quad * 4;
    const int vbc = (vb <= VD - 4) ? vb : (VD - 4);
    const float4 ob = *(const float4*)(outb + vbc);
#pragma unroll
    for (int nt = 0; nt < 4; nt++) {
#pragma unroll
      for (int reg = 0; reg < 4; reg++) {
        const int v = vb + reg;
        if (v < VD) {
          const float obv = (reg == 0) ? ob.x : (reg == 1) ? ob.y : (reg == 2) ? ob.z : ob.w;
          const float val = acc[mt][nt][reg] + obv;
          const u64 key = ((u64)enc32(val) << 32) | (u64)(0xFFFFFFFFu - (unsigned)v);
          top2(key, best[nt], run[nt]);
        }
      }
    }
  }

#pragma unroll
  for (int nt = 0; nt < 4; nt++) {
    u64 ob = shfl64(best[nt], 16), orr = shfl64(run[nt], 16);
    top2(ob, best[nt], run[nt]); top2(orr, best[nt], run[nt]);
    ob = shfl64(best[nt], 32); orr = shfl64(run[nt], 32);
    top2(ob, best[nt], run[nt]); top2(orr, best[nt], run[nt]);
  }

  // lane l writes b = l  (nt = l>>4, col = l&15)
  u64 wb = best[0], wr = run[0];
  if (quad == 1) { wb = best[1]; wr = run[1]; }
  if (quad == 2) { wb = best[2]; wr = run[2]; }
  if (quad == 3) { wb = best[3]; wr = run[3]; }
  u64* dst = bbuf + (size_t)lane * (NM32 * 2) + (size_t)m32 * 2;
  dst[0] = wb; dst[1] = wr;
}

// ---------------------------------------------------------------------------
// k_fin2: per batch row: approx max over keys -> margin candidates -> exact
// fp32 rescore -> token + next decoder x. Wave-shuffle reductions (2 barriers
// each instead of 8) and vectorized scans/rescore.
// ---------------------------------------------------------------------------
__global__ __launch_bounds__(256) void k_fin2(
    const u64* __restrict__ bbuf, const float* __restrict__ hT,
    const float* __restrict__ outW, const float* __restrict__ outb,
    const float* __restrict__ emb,
    float* __restrict__ out_row, float* __restrict__ xdec)
{
  const int b = blockIdx.x;
  const int tid = threadIdx.x;
  const int w = tid >> 6, lane = tid & 63;
  const u64* keys = bbuf + (size_t)b * (NM32 * 2);

  // pass 1: approximate max over all keys (vectorized)
  u64 local = 0ull;
  {
    const ulonglong2* k2 = (const ulonglong2*)keys;
    for (int i = tid; i < NM32; i += 256) {
      const ulonglong2 v = k2[i];
      local = umax64(local, umax64(v.x, v.y));
    }
  }
  for (int mm = 1; mm <= 32; mm <<= 1) local = umax64(local, shfl64(local, mm));

  __shared__ u64 wmax[4];
  __shared__ unsigned s_te;
  __shared__ int s_n;
  if (lane == 0) wmax[w] = local;
  __syncthreads();
  if (tid == 0) {
    const u64 mx = umax64(umax64(wmax[0], wmax[1]), umax64(wmax[2], wmax[3]));
    const float mv = dec32((unsigned)(mx >> 32));
    s_te = enc32(mv - MARGIN);
    s_n = 0;
  }
  __syncthreads();
  const unsigned te = s_te;

  // pass 2: collect margin candidates
  __shared__ int cand[256];
  for (int i = tid; i < NM32 * 2; i += 256) {
    const u64 k = keys[i];
    if ((unsigned)(k >> 32) >= te && k != 0ull) {
      const int slot = atomicAdd(&s_n, 1);
      if (slot < 256) cand[slot] = (int)(0xFFFFFFFFu - (unsigned)k);
    }
  }
  __syncthreads();
  const int n = min(s_n, 256);

  // exact fp32 rescore of candidates (float4-vectorized)
  u64 bk = 0ull;
  if (tid < n) {
    const int v = cand[tid];
    const float4* wr4 = (const float4*)(outW + (size_t)v * HD);
    float acc = 0.f;
    for (int c = 0; c < KC; c++) {
      const float4 wv = wr4[c];
      const float4 hv = *(const float4*)(hT + c * 256 + b * 4);
      acc += wv.x * hv.x + wv.y * hv.y + wv.z * hv.z + wv.w * hv.w;
    }
    acc += outb[v];
    bk = ((u64)enc32(acc) << 32) | (u64)(0xFFFFFFFFu - (unsigned)v);
  }
  for (int mm = 1; mm <= 32; mm <<= 1) bk = umax64(bk, shfl64(bk, mm));
  if (lane == 0) wmax[w] = bk;
  __syncthreads();

  __shared__ int s_id;
  if (tid == 0) {
    const u64 mx = umax64(umax64(wmax[0], wmax[1]), umax64(wmax[2], wmax[3]));
    const int id = (int)(0xFFFFFFFFu - (unsigned)(mx & 0xFFFFFFFFull));
    out_row[b] = (float)id;
    s_id = id;
  }
  __syncthreads();

  const int id = s_id;
  for (int k = tid; k < HD; k += 256)
    xdec[tidx(k, b)] = fmaxf(emb[(size_t)id * HD + k], 0.f);
}

// ---------------------------------------------------------------------------
extern "C" void kernel_launch(void* const* d_in, const int* in_sizes, int n_in,
                              void* d_out, int out_size, void* d_ws, size_t ws_size,
                              hipStream_t stream) {
  const int*   input  = (const int*)d_in[0];
  const float* emb    = (const float*)d_in[1];
  const float* eWih   = (const float*)d_in[2];
  const float* eWhh   = (const float*)d_in[3];
  const float* eBih   = (const float*)d_in[4];
  const float* eBhh   = (const float*)d_in[5];
  const float* dWih   = (const float*)d_in[6];
  const float* dWhh   = (const float*)d_in[7];
  const float* dBih   = (const float*)d_in[8];
  const float* dBhh   = (const float*)d_in[9];
  const float* outW   = (const float*)d_in[10];
  const float* outb   = (const float*)d_in[11];
  float* out = (float*)d_out;

  const size_t wpBytes = (size_t)NT16 * 10 * 1024;   // 64,020,480
  size_t need = wpBytes + 3201024 + 40960 + 5145600 + 6 * 256;
  const bool packed = ws_size >= need;

  size_t off = 0;
  auto take = [&](size_t nbytes) -> char* {
    char* p = (char*)d_ws + off;
    off += (nbytes + 255) & ~(size_t)255;
    return p;
  };

  unsigned* Wp = packed ? (unsigned*)take(wpBytes) : nullptr;
  u64*      bbuf = (u64*)take((size_t)BD * NM32 * 2 * 8);
  unsigned* hbp  = (unsigned*)take(40960);
  float* hA   = (float*)take(76800);
  float* hB   = (float*)take(76800);
  float* xdec = (float*)take(76800);
  float* xall = (float*)take((size_t)LD * 76800);

  if (packed) k_pack<<<NT16, 256, 0, stream>>>(outW, Wp);
  k_prep<<<dim3(LD, BD), 320, 0, stream>>>(input, emb, xall);
  k_init<<<BD, 320, 0, stream>>>(hA, emb, xdec, hbp);

  // ---- encoder ----
  for (int t = 0; t < LD; t++) {
    float* hin  = (t & 1) ? hB : hA;
    float* hout = (t & 1) ? hA : hB;
    k_gru<false><<<75, 768, 0, stream>>>(xall + t * (KC * 256), hin,
                                         eWih, eWhh, eBih, eBhh, hout, hbp);
  }
  // enc_h in hA

  // ---- decoder ----
  for (int s = 0; s < LD; s++) {
    float* hin  = (s & 1) ? hB : hA;
    float* hout = (s & 1) ? hA : hB;
    k_gru<true><<<75, 768, 0, stream>>>(xdec, hin, dWih, dWhh, dBih, dBhh, hout, hbp);
    if (packed)
      k_projbf<true><<<782, 256, 0, stream>>>(Wp, outW, hbp, outb, bbuf);
    else
      k_projbf<false><<<782, 256, 0, stream>>>(Wp, outW, hbp, outb, bbuf);
    k_fin2<<<BD, 256, 0, stream>>>(bbuf, hout, outW, outb, emb, out + s * BD, xdec);
  }
}

// Round 2
// 6058.828 us; speedup vs baseline: 1.1268x; 1.0793x over previous
//
#include <hip/hip_runtime.h>
#include <hip/hip_cooperative_groups.h>

namespace cg = cooperative_groups;

#define HD 300
#define KC 75
#define BD 64
#define VD 100000
#define LD 64
#define NM32 3126            // number of 32-row vocab groups (3126*32 = 100032)
#define NT16 6252            // number of 16-row vocab tiles
#define MARGIN 0.05f
#define NBLK 521             // 521 blocks * 6 waves = 3126 = NM32 exactly
#define NTHR 384

typedef unsigned long long u64;
typedef short short8 __attribute__((ext_vector_type(8)));
typedef float f32x4 __attribute__((ext_vector_type(4)));

__device__ __forceinline__ float sigm(float x) { return 1.0f / (1.0f + expf(-x)); }

// Transposed k-chunked layout: T[kc][b][e] = X[b][4*kc+e].
__device__ __forceinline__ int tidx(int k, int b) {
  return (k >> 2) * 256 + b * 4 + (k & 3);
}

__device__ __forceinline__ unsigned enc32(float f) {
  unsigned u = __float_as_uint(f);
  return (u & 0x80000000u) ? ~u : (u | 0x80000000u);
}
__device__ __forceinline__ float dec32(unsigned e) {
  unsigned u = (e & 0x80000000u) ? (e & 0x7FFFFFFFu) : ~e;
  return __uint_as_float(u);
}
__device__ __forceinline__ unsigned short f2bf(float f) {   // RNE
  unsigned u = __float_as_uint(f);
  unsigned r = u + 0x7FFFu + ((u >> 16) & 1u);
  return (unsigned short)(r >> 16);
}
__device__ __forceinline__ u64 shfl64(u64 v, int m) {
  int lo = __shfl_xor((int)(unsigned)v, m, 64);
  int hi = __shfl_xor((int)(unsigned)(v >> 32), m, 64);
  return ((u64)(unsigned)hi << 32) | (unsigned)lo;
}
__device__ __forceinline__ u64 umax64(u64 a, u64 b) { return a > b ? a : b; }
__device__ __forceinline__ void top2(u64 k, u64& b, u64& r) {
  if (k > b) { r = b; b = k; } else if (k > r) r = k;
}

// Shared-memory union: one 40 KB region reused by all phases.
union __align__(16) SM {
  unsigned hlds[10240];                                     // proj B-staging
  struct { float sg[2][3][4][64]; float hsh[4][64]; } g;    // gru gates + h
  struct { u64 wmax[8]; int cand[256]; unsigned te; int n; int id; } f;  // fin
};

// ---------------------------------------------------------------------------
// d_gru: one block (6 waves) computes 4 h-rows (i0..i0+3). Wave (m,g) does one
// of the 6 row-dot roles; epilogue on waves 0..3; optional bf16 pack of the
// fresh rows into hbp (MFMA B-fragment order).
// ---------------------------------------------------------------------------
__device__ __forceinline__ void d_gru(
    int blk, int tid,
    const float* __restrict__ xT, const float* __restrict__ hT_in,
    const float* __restrict__ W_ih, const float* __restrict__ W_hh,
    const float* __restrict__ b_ih, const float* __restrict__ b_hh,
    float* __restrict__ hT_out, unsigned* __restrict__ hbp, bool pack,
    SM* sm)
{
  const int w = __builtin_amdgcn_readfirstlane(tid >> 6);   // 0..5
  const int b = tid & 63;
  const int m = w & 1;
  const int g = w >> 1;
  const int i0 = blk * 4;

  const float* src = m ? hT_in : xT;
  const float* M   = m ? W_hh : W_ih;
  const float* row0 = M + (size_t)(g * HD + i0) * HD;

  float4 a0 = {0,0,0,0}, a1 = {0,0,0,0}, a2 = {0,0,0,0}, a3 = {0,0,0,0};

  for (int kc = 0; kc < KC; kc++) {
    const float4 s  = *(const float4*)(src + kc * 256 + b * 4);
    const float4 w0 = *(const float4*)(row0 + kc * 4);
    const float4 w1 = *(const float4*)(row0 + HD + kc * 4);
    const float4 w2 = *(const float4*)(row0 + 2 * HD + kc * 4);
    const float4 w3 = *(const float4*)(row0 + 3 * HD + kc * 4);
    a0.x += w0.x * s.x; a0.y += w0.y * s.y; a0.z += w0.z * s.z; a0.w += w0.w * s.w;
    a1.x += w1.x * s.x; a1.y += w1.y * s.y; a1.z += w1.z * s.z; a1.w += w1.w * s.w;
    a2.x += w2.x * s.x; a2.y += w2.y * s.y; a2.z += w2.z * s.z; a2.w += w2.w * s.w;
    a3.x += w3.x * s.x; a3.y += w3.y * s.y; a3.z += w3.z * s.z; a3.w += w3.w * s.w;
  }

  const float* bias = m ? b_hh : b_ih;
  sm->g.sg[m][g][0][b] = (a0.x + a0.y) + (a0.z + a0.w) + bias[g * HD + i0 + 0];
  sm->g.sg[m][g][1][b] = (a1.x + a1.y) + (a1.z + a1.w) + bias[g * HD + i0 + 1];
  sm->g.sg[m][g][2][b] = (a2.x + a2.y) + (a2.z + a2.w) + bias[g * HD + i0 + 2];
  sm->g.sg[m][g][3][b] = (a3.x + a3.y) + (a3.z + a3.w) + bias[g * HD + i0 + 3];
  __syncthreads();

  if (w < 4) {
    const int r = w;
    const int i = i0 + r;
    const float rr = sigm(sm->g.sg[0][0][r][b] + sm->g.sg[1][0][r][b]);
    const float zz = sigm(sm->g.sg[0][1][r][b] + sm->g.sg[1][1][r][b]);
    const float nn = tanhf(sm->g.sg[0][2][r][b] + rr * sm->g.sg[1][2][r][b]);
    const float hp = hT_in[tidx(i, b)];
    const float h  = (1.f - zz) * nn + zz * hp;
    hT_out[tidx(i, b)] = h;
    sm->g.hsh[r][b] = h;
  }

  if (pack) {
    __syncthreads();
    if (w < 2) {
      const int k = i0 + 2 * w;
      const unsigned outp =
          (unsigned)f2bf(sm->g.hsh[2 * w][b]) | ((unsigned)f2bf(sm->g.hsh[2 * w + 1][b]) << 16);
      const int kt = k >> 5;
      const int q  = (k >> 3) & 3;
      const int p  = (k >> 1) & 3;
      const int nt = b >> 4;
      const int ln = q * 16 + (b & 15);
      hbp[((kt * 4 + nt) << 8) + ln * 4 + p] = outp;
    }
  }
}

// ---------------------------------------------------------------------------
// d_proj: wave handles m32 = blk*6 + w (always < NM32 by construction).
// MFMA projection with register double-buffered A-fragments + top2 epilogue.
// ---------------------------------------------------------------------------
template <bool PACKED>
__device__ __forceinline__ void d_proj(
    int blk, int tid,
    const unsigned* __restrict__ Wp, const float* __restrict__ outW,
    const unsigned* __restrict__ hbp, const float* __restrict__ outb,
    u64* __restrict__ bbuf, SM* sm)
{
  const int w = __builtin_amdgcn_readfirstlane(tid >> 6);   // 0..5
  const int lane = tid & 63;
  const int m32 = blk * 6 + w;
  const int t0 = m32 * 2;
  const int quad = lane >> 4;

  f32x4 acc[2][4];
#pragma unroll
  for (int mt = 0; mt < 2; mt++)
#pragma unroll
    for (int nt = 0; nt < 4; nt++) acc[mt][nt] = f32x4{0.f, 0.f, 0.f, 0.f};

  auto LOADA = [&](short8* dst, int kt) {
    if (PACKED) {
#pragma unroll
      for (int mt = 0; mt < 2; mt++)
        dst[mt] = *(const short8*)(Wp + ((size_t)(t0 + mt) * 10 + kt) * 256 + lane * 4);
    } else {
#pragma unroll
      for (int mt = 0; mt < 2; mt++) {
        const int v = (t0 + mt) * 16 + (lane & 15);
        const int kb = kt * 32 + quad * 8;
        const int vc = (v < VD) ? v : (VD - 1);
        short8 tmp;
#pragma unroll
        for (int e = 0; e < 8; e++) {
          const int kk = kb + e;
          const float f = (kk < HD && v < VD) ? outW[(size_t)vc * HD + kk] : 0.f;
          tmp[e] = (short)f2bf(f);
        }
        dst[mt] = tmp;
      }
    }
  };

  auto COMPUTE = [&](short8* a, int kt) {
#pragma unroll
    for (int nt = 0; nt < 4; nt++) {
      const short8 bf = *(const short8*)(&sm->hlds[((kt * 4 + nt) << 8) + lane * 4]);
      acc[0][nt] = __builtin_amdgcn_mfma_f32_16x16x32_bf16(a[0], bf, acc[0][nt], 0, 0, 0);
      acc[1][nt] = __builtin_amdgcn_mfma_f32_16x16x32_bf16(a[1], bf, acc[1][nt], 0, 0, 0);
    }
  };

  short8 aA[2], aB[2];
  LOADA(aA, 0);                               // in flight during staging

  {
    const uint4* hb4 = (const uint4*)hbp;
    uint4* hl4 = (uint4*)sm->hlds;
    for (int i = tid; i < 2560; i += NTHR) hl4[i] = hb4[i];
  }
  __syncthreads();

#pragma unroll
  for (int kp = 0; kp < 5; kp++) {
    LOADA(aB, 2 * kp + 1);
    COMPUTE(aA, 2 * kp);
    if (kp < 4) LOADA(aA, 2 * kp + 2);
    COMPUTE(aB, 2 * kp + 1);
  }

  // ---- epilogue: top2 per batch column ----
  const int m0 = m32 * 32;
  u64 best[4], run[4];
#pragma unroll
  for (int nt = 0; nt < 4; nt++) { best[nt] = 0ull; run[nt] = 0ull; }

#pragma unroll
  for (int mt = 0; mt < 2; mt++) {
    const int vb = m0 + mt * 16 + quad * 4;
    const int vbc = (vb <= VD - 4) ? vb : (VD - 4);
    const float4 ob = *(const float4*)(outb + vbc);
#pragma unroll
    for (int nt = 0; nt < 4; nt++) {
#pragma unroll
      for (int reg = 0; reg < 4; reg++) {
        const int v = vb + reg;
        if (v < VD) {
          const float obv = (reg == 0) ? ob.x : (reg == 1) ? ob.y : (reg == 2) ? ob.z : ob.w;
          const float val = acc[mt][nt][reg] + obv;
          const u64 key = ((u64)enc32(val) << 32) | (u64)(0xFFFFFFFFu - (unsigned)v);
          top2(key, best[nt], run[nt]);
        }
      }
    }
  }

#pragma unroll
  for (int nt = 0; nt < 4; nt++) {
    u64 ob = shfl64(best[nt], 16), orr = shfl64(run[nt], 16);
    top2(ob, best[nt], run[nt]); top2(orr, best[nt], run[nt]);
    ob = shfl64(best[nt], 32); orr = shfl64(run[nt], 32);
    top2(ob, best[nt], run[nt]); top2(orr, best[nt], run[nt]);
  }

  u64 wb = best[0], wr = run[0];
  if (quad == 1) { wb = best[1]; wr = run[1]; }
  if (quad == 2) { wb = best[2]; wr = run[2]; }
  if (quad == 3) { wb = best[3]; wr = run[3]; }
  u64* dst = bbuf + (size_t)lane * (NM32 * 2) + (size_t)m32 * 2;
  dst[0] = wb; dst[1] = wr;
}

// ---------------------------------------------------------------------------
// d_fin: per batch row b: approx max -> margin candidates -> exact rescore ->
// token + next decoder x. 384 threads (6 waves).
// ---------------------------------------------------------------------------
__device__ __forceinline__ void d_fin(
    int b, int tid,
    const u64* __restrict__ bbuf, const float* __restrict__ hT,
    const float* __restrict__ outW, const float* __restrict__ outb,
    const float* __restrict__ emb,
    float* __restrict__ out_row, float* __restrict__ xdec, SM* sm)
{
  const int w = tid >> 6, lane = tid & 63;
  const u64* keys = bbuf + (size_t)b * (NM32 * 2);

  u64 local = 0ull;
  {
    const ulonglong2* k2 = (const ulonglong2*)keys;
    for (int i = tid; i < NM32; i += NTHR) {
      const ulonglong2 v = k2[i];
      local = umax64(local, umax64(v.x, v.y));
    }
  }
  for (int mm = 1; mm <= 32; mm <<= 1) local = umax64(local, shfl64(local, mm));
  if (lane == 0) sm->f.wmax[w] = local;
  __syncthreads();
  if (tid == 0) {
    u64 mx = 0ull;
    for (int i = 0; i < 6; i++) mx = umax64(mx, sm->f.wmax[i]);
    sm->f.te = enc32(dec32((unsigned)(mx >> 32)) - MARGIN);
    sm->f.n = 0;
  }
  __syncthreads();
  const unsigned te = sm->f.te;

  for (int i = tid; i < NM32 * 2; i += NTHR) {
    const u64 k = keys[i];
    if ((unsigned)(k >> 32) >= te && k != 0ull) {
      const int slot = atomicAdd(&sm->f.n, 1);
      if (slot < 256) sm->f.cand[slot] = (int)(0xFFFFFFFFu - (unsigned)k);
    }
  }
  __syncthreads();
  const int n = min(sm->f.n, 256);

  u64 bk = 0ull;
  if (tid < n) {
    const int v = sm->f.cand[tid];
    const float4* wr4 = (const float4*)(outW + (size_t)v * HD);
    float acc = 0.f;
    for (int c = 0; c < KC; c++) {
      const float4 wv = wr4[c];
      const float4 hv = *(const float4*)(hT + c * 256 + b * 4);
      acc += wv.x * hv.x + wv.y * hv.y + wv.z * hv.z + wv.w * hv.w;
    }
    acc += outb[v];
    bk = ((u64)enc32(acc) << 32) | (u64)(0xFFFFFFFFu - (unsigned)v);
  }
  for (int mm = 1; mm <= 32; mm <<= 1) bk = umax64(bk, shfl64(bk, mm));
  if (lane == 0) sm->f.wmax[w] = bk;
  __syncthreads();
  if (tid == 0) {
    u64 mx = 0ull;
    for (int i = 0; i < 6; i++) mx = umax64(mx, sm->f.wmax[i]);
    const int id = (int)(0xFFFFFFFFu - (unsigned)(mx & 0xFFFFFFFFull));
    out_row[b] = (float)id;
    sm->f.id = id;
  }
  __syncthreads();

  const int id = sm->f.id;
  for (int k = tid; k < HD; k += NTHR)
    xdec[tidx(k, b)] = fmaxf(emb[(size_t)id * HD + k], 0.f);
}

// ---------------------------------------------------------------------------
// k_mega: the whole encoder + decoder as ONE cooperative kernel.
// 521 blocks x 384 threads; grid syncs replace dispatch boundaries.
// ---------------------------------------------------------------------------
template <bool PACKED>
__global__ __launch_bounds__(NTHR) void k_mega(
    const float* __restrict__ xall, float* __restrict__ hA, float* __restrict__ hB,
    float* __restrict__ xdec, unsigned* __restrict__ hbp, u64* __restrict__ bbuf,
    const float* __restrict__ eWih, const float* __restrict__ eWhh,
    const float* __restrict__ eBih, const float* __restrict__ eBhh,
    const float* __restrict__ dWih, const float* __restrict__ dWhh,
    const float* __restrict__ dBih, const float* __restrict__ dBhh,
    const unsigned* __restrict__ Wp, const float* __restrict__ outW,
    const float* __restrict__ outb, const float* __restrict__ emb,
    float* __restrict__ out)
{
  __shared__ SM sm;
  cg::grid_group grid = cg::this_grid();
  const int blk = blockIdx.x;
  const int tid = threadIdx.x;

  // ---- encoder ----
  for (int t = 0; t < LD; t++) {
    const float* hin = (t & 1) ? hB : hA;
    float* hout = (t & 1) ? hA : hB;
    if (blk < 75)
      d_gru(blk, tid, xall + t * (KC * 256), hin, eWih, eWhh, eBih, eBhh,
            hout, nullptr, false, &sm);
    __threadfence();
    grid.sync();
  }
  // enc_h in hA

  // ---- decoder ----
  for (int s = 0; s < LD; s++) {
    const float* hin = (s & 1) ? hB : hA;
    float* hout = (s & 1) ? hA : hB;
    if (blk < 75)
      d_gru(blk, tid, xdec, hin, dWih, dWhh, dBih, dBhh, hout, hbp, true, &sm);
    __threadfence();
    grid.sync();

    d_proj<PACKED>(blk, tid, Wp, outW, hbp, outb, bbuf, &sm);
    __threadfence();
    grid.sync();

    if (blk < BD)
      d_fin(blk, tid, bbuf, hout, outW, outb, emb, out + s * BD, xdec, &sm);
    __threadfence();
    grid.sync();
  }
}

// ---------------------------------------------------------------------------
// Fallback multi-dispatch wrappers (same device functions).
// ---------------------------------------------------------------------------
template <bool PACK>
__global__ __launch_bounds__(NTHR) void k_gru_g(
    const float* __restrict__ xT, const float* __restrict__ hin,
    const float* __restrict__ Wih, const float* __restrict__ Whh,
    const float* __restrict__ bih, const float* __restrict__ bhh,
    float* __restrict__ hout, unsigned* __restrict__ hbp)
{
  __shared__ SM sm;
  d_gru(blockIdx.x, threadIdx.x, xT, hin, Wih, Whh, bih, bhh, hout, hbp, PACK, &sm);
}

template <bool PACKED>
__global__ __launch_bounds__(NTHR) void k_proj_g(
    const unsigned* __restrict__ Wp, const float* __restrict__ outW,
    const unsigned* __restrict__ hbp, const float* __restrict__ outb,
    u64* __restrict__ bbuf)
{
  __shared__ SM sm;
  d_proj<PACKED>(blockIdx.x, threadIdx.x, Wp, outW, hbp, outb, bbuf, &sm);
}

__global__ __launch_bounds__(NTHR) void k_fin_g(
    const u64* __restrict__ bbuf, const float* __restrict__ hT,
    const float* __restrict__ outW, const float* __restrict__ outb,
    const float* __restrict__ emb,
    float* __restrict__ out_row, float* __restrict__ xdec)
{
  __shared__ SM sm;
  d_fin(blockIdx.x, threadIdx.x, bbuf, hT, outW, outb, emb, out_row, xdec, &sm);
}

// ---------------------------------------------------------------------------
// k_prep / k_init / k_pack: unchanged setup kernels.
// ---------------------------------------------------------------------------
__global__ __launch_bounds__(320) void k_prep(
    const int* __restrict__ input, const float* __restrict__ emb,
    float* __restrict__ xall)
{
  const int t = blockIdx.x, b = blockIdx.y;
  const int k = threadIdx.x;
  if (k >= HD) return;
  const int id = input[t * BD + b];
  xall[t * (KC * 256) + tidx(k, b)] = emb[(size_t)id * HD + k];
}

__global__ __launch_bounds__(320) void k_init(
    float* __restrict__ hT, const float* __restrict__ emb, float* __restrict__ xdec,
    unsigned* __restrict__ hbp)
{
  const int b = blockIdx.x;
  const int k = threadIdx.x;
  const int gi = b * 320 + k;
  if (gi < 10240) hbp[gi] = 0u;
  if (k >= HD) return;
  hT[tidx(k, b)] = 0.f;
  xdec[tidx(k, b)] = fmaxf(emb[k], 0.f);
}

__global__ __launch_bounds__(256) void k_pack(
    const float* __restrict__ outW, unsigned* __restrict__ Wp)
{
  const int t16 = blockIdx.x;
  const int d = threadIdx.x;          // 0..255: lane = d>>2, pair p = d&3
  const int lane = d >> 2, p = d & 3;
  const int v = t16 * 16 + (lane & 15);
  for (int kt = 0; kt < 10; kt++) {
    const int k = kt * 32 + (lane >> 4) * 8 + 2 * p;
    float f0 = 0.f, f1 = 0.f;
    if (v < VD) {
      if (k < HD)     f0 = outW[(size_t)v * HD + k];
      if (k + 1 < HD) f1 = outW[(size_t)v * HD + k + 1];
    }
    const unsigned outp = (unsigned)f2bf(f0) | ((unsigned)f2bf(f1) << 16);
    Wp[((size_t)t16 * 10 + kt) * 256 + d] = outp;
  }
}

// ---------------------------------------------------------------------------
extern "C" void kernel_launch(void* const* d_in, const int* in_sizes, int n_in,
                              void* d_out, int out_size, void* d_ws, size_t ws_size,
                              hipStream_t stream) {
  const int*   input  = (const int*)d_in[0];
  const float* emb    = (const float*)d_in[1];
  const float* eWih   = (const float*)d_in[2];
  const float* eWhh   = (const float*)d_in[3];
  const float* eBih   = (const float*)d_in[4];
  const float* eBhh   = (const float*)d_in[5];
  const float* dWih   = (const float*)d_in[6];
  const float* dWhh   = (const float*)d_in[7];
  const float* dBih   = (const float*)d_in[8];
  const float* dBhh   = (const float*)d_in[9];
  const float* outW   = (const float*)d_in[10];
  const float* outb   = (const float*)d_in[11];
  float* out = (float*)d_out;

  const size_t wpBytes = (size_t)NT16 * 10 * 1024;   // 64,020,480
  size_t need = wpBytes + 3201024 + 40960 + 5145600 + 6 * 256;
  const bool packed = ws_size >= need;

  size_t off = 0;
  auto take = [&](size_t nbytes) -> char* {
    char* p = (char*)d_ws + off;
    off += (nbytes + 255) & ~(size_t)255;
    return p;
  };

  unsigned* Wp = packed ? (unsigned*)take(wpBytes) : nullptr;
  u64*      bbuf = (u64*)take((size_t)BD * NM32 * 2 * 8);
  unsigned* hbp  = (unsigned*)take(40960);
  float* hA   = (float*)take(76800);
  float* hB   = (float*)take(76800);
  float* xdec = (float*)take(76800);
  float* xall = (float*)take((size_t)LD * 76800);

  using MegaFn = void (*)(const float*, float*, float*, float*, unsigned*, u64*,
                          const float*, const float*, const float*, const float*,
                          const float*, const float*, const float*, const float*,
                          const unsigned*, const float*, const float*, const float*,
                          float*);

  // one-time capability check (host-side queries only; graph-capture safe)
  static int s_mega = -2;
  if (s_mega == -2) {
    s_mega = 0;
    int coop = 0;
    if (hipDeviceGetAttribute(&coop, hipDeviceAttributeCooperativeLaunch, 0) == hipSuccess && coop) {
      int ncu = 0;
      hipDeviceGetAttribute(&ncu, hipDeviceAttributeMultiprocessorCount, 0);
      int occ = 0;
      MegaFn fp = k_mega<true>;
      if (hipOccupancyMaxActiveBlocksPerMultiprocessor(
              &occ, reinterpret_cast<const void*>(fp), NTHR, 0) == hipSuccess &&
          occ * ncu >= NBLK)
        s_mega = 1;
    }
  }

  if (packed) k_pack<<<NT16, 256, 0, stream>>>(outW, Wp);
  k_prep<<<dim3(LD, BD), 320, 0, stream>>>(input, emb, xall);
  k_init<<<BD, 320, 0, stream>>>(hA, emb, xdec, hbp);

  bool done = false;
  if (s_mega == 1) {
    const float* xall_c = xall;
    const unsigned* Wp_c = Wp;
    void* args[19] = {
      (void*)&xall_c, (void*)&hA, (void*)&hB, (void*)&xdec, (void*)&hbp, (void*)&bbuf,
      (void*)&eWih, (void*)&eWhh, (void*)&eBih, (void*)&eBhh,
      (void*)&dWih, (void*)&dWhh, (void*)&dBih, (void*)&dBhh,
      (void*)&Wp_c, (void*)&outW, (void*)&outb, (void*)&emb, (void*)&out };
    MegaFn fn = packed ? (MegaFn)k_mega<true> : (MegaFn)k_mega<false>;
    hipError_t e = hipLaunchCooperativeKernel(
        reinterpret_cast<const void*>(fn), dim3(NBLK), dim3(NTHR), args, 0, stream);
    done = (e == hipSuccess);
  }

  if (!done) {
    // ---- fallback: multi-dispatch path ----
    for (int t = 0; t < LD; t++) {
      float* hin  = (t & 1) ? hB : hA;
      float* hout = (t & 1) ? hA : hB;
      k_gru_g<false><<<75, NTHR, 0, stream>>>(xall + t * (KC * 256), hin,
                                              eWih, eWhh, eBih, eBhh, hout, hbp);
    }
    for (int s = 0; s < LD; s++) {
      float* hin  = (s & 1) ? hB : hA;
      float* hout = (s & 1) ? hA : hB;
      k_gru_g<true><<<75, NTHR, 0, stream>>>(xdec, hin, dWih, dWhh, dBih, dBhh, hout, hbp);
      if (packed)
        k_proj_g<true><<<NBLK, NTHR, 0, stream>>>(Wp, outW, hbp, outb, bbuf);
      else
        k_proj_g<false><<<NBLK, NTHR, 0, stream>>>(Wp, outW, hbp, outb, bbuf);
      k_fin_g<<<BD, NTHR, 0, stream>>>(bbuf, hout, outW, outb, emb, out + s * BD, xdec);
    }
  }
}